// Round 14
// baseline (104.300 us; speedup 1.0000x reference)
//
#include <hip/hip_runtime.h>
#include <hip/hip_bf16.h>

// ---------------------------------------------------------------------------
// Metric_Loss: two fused (X X^T/128 -> exp(1+.) -> row-sum) passes + pair combine.
// B=8192, E=128, P=4096.  Output: scalar f32 = metric_tt + metric_st.
//
// Round 14: ZERO-BARRIER gemm. N-only wave split (wave w owns cols w*16..+16
// of each 64-col tile) -> each wave stages only ITS 16 B-rows (2KB) into a
// PRIVATE 3-slot LDS ring via global_load_lds, depth-2 prefetch, and waits
// only on its own vmcnt. No s_barrier / cross-wave sync after launch. A-frags
// (4 m-frags, K=128) hoisted from global once. Block-wide DS reads per tile
// halve (no wr-pair duplication); col atomics halve. MX-fp8 16x16x128,
// exp2 pre-scale sqrt(log2e/128), symmetry wrap-pairing as R8.
//
// ws layout:
//   [0, 1MB)        Xt fp8    [8192][128]   scaled by sqrt(log2e/128)
//   [1MB, 2MB)      Xm fp8    [8192][128]   (mixed: even=text, odd=shape[r>>1])
//   [2MB, 2MB+64KB) R f32     [2][8192]     row sums of exp(1+D)
// ---------------------------------------------------------------------------

#define B_ROWS 8192
#define E_COLS 128
#define P_PAIRS 4096
#define NSTRIP 128              // 64-row strips
#define NH 8                    // h-splits per strip

using f32x4 = __attribute__((ext_vector_type(4))) float;
using i32x8 = __attribute__((ext_vector_type(8))) int;

// sqrt(log2(e)/128): MFMA yields acc = D*log2(e); exp(1+D) = e * exp2(acc)
#define BF_SCALE 0.106164482742544f
#define EULER    2.718281828459045f
#define SCALE1   0x7f            // E8M0 exponent 127 -> 2^0 (unit scale)

__device__ __forceinline__ unsigned pk4_fp8(float a, float b, float c, float d) {
    unsigned v = 0;
    v = __builtin_amdgcn_cvt_pk_fp8_f32(a * BF_SCALE, b * BF_SCALE, v, false);
    v = __builtin_amdgcn_cvt_pk_fp8_f32(c * BF_SCALE, d * BF_SCALE, v, true);
    return v;
}

// K=128 fragment straight from global (row-major, unswizzled).
__device__ __forceinline__ i32x8 load_frag32_g(const char* rowbase, int k32) {
    union { i32x8 v; int4 h[2]; } u;
    u.h[0] = *(const int4*)(rowbase + k32);
    u.h[1] = *(const int4*)(rowbase + k32 + 16);
    return u.v;
}

// --------------------------- conversion kernel -----------------------------
__global__ void convert_kernel(const float* __restrict__ text,
                               const float* __restrict__ shape,
                               unsigned* __restrict__ Xt,
                               unsigned* __restrict__ Xm,
                               float* __restrict__ R,
                               float* __restrict__ out) {
    int idx = blockIdx.x * blockDim.x + threadIdx.x;     // 4 elements per thread
    if (idx >= B_ROWS * E_COLS / 4) return;
    if (idx < 4096) {                                    // zero R (2*8192 f32)
        float4 z; z.x = z.y = z.z = z.w = 0.f;
        ((float4*)R)[idx] = z;
    }
    if (idx == 0) *out = 0.f;
    int e = idx * 4;
    float4 t = *(const float4*)(text + e);
    unsigned tp = pk4_fp8(t.x, t.y, t.z, t.w);
    Xt[idx] = tp;
    int row = e >> 7;
    if (row & 1) {
        int col = e & 127;
        float4 s = *(const float4*)(shape + (row >> 1) * E_COLS + col);
        Xm[idx] = pk4_fp8(s.x, s.y, s.z, s.w);
    } else {
        Xm[idx] = tp;
    }
}

// --------------------------- fused GEMM + rowsum (wave-independent) --------
// Block = (strip bm, split h in 0..7, layer l). Strip = 64 A-rows.
// Tiles k=0..7: t = t0 + 8k, bn=(bm+t)&127, t0=(h==0)?8:h; each unordered
// pair once; t==64 (h==0,k==7) gated by g7 for bm>=64; diag (h==0) extra.
// Wave w computes rows 0..63 x cols [w*16,w*16+16) of each tile.
__launch_bounds__(256, 5)
__global__ void gemm_rowsum_kernel(const unsigned char* __restrict__ Xt,
                                   const unsigned char* __restrict__ Xm,
                                   float* __restrict__ R) {
    const int bm = blockIdx.x, h = blockIdx.y, l = blockIdx.z;
    const char* gX = (const char*)(l ? Xm : Xt);

    __shared__ __align__(16) char lds[4][3][16 * 128];   // [wave][ring][2KB]
    const int tid  = threadIdx.x;
    const int lane = tid & 63;
    const int w    = tid >> 6;

    const int t0 = (h == 0) ? NH : h;
    const float g7 = (h == 0 && bm >= 64) ? 0.f : 1.f;   // gate for k==7

    const int lrow = lane & 15;                  // row within wave's 16-row slice
    const int kb   = (lane >> 4) * 32;           // byte offset of lane's K-slice

    // per-wave private stage: 16 rows [w*16, w*16+16) of tile bn -> ring slot
    auto stage = [&](int bn, char* dst) {
        const char* base = gX + (size_t)bn * 8192 + w * (16 * 128);
#pragma unroll
        for (int it = 0; it < 2; ++it) {
            int sr  = it * 8 + (lane >> 3);      // source local row 0..15
            int cb  = (lane & 7) * 16;
            int src = sr * 128 + (cb ^ ((sr & 7) << 4));
            __builtin_amdgcn_global_load_lds(
                (const __attribute__((address_space(1))) void*)(base + src),
                (__attribute__((address_space(3))) void*)(dst + it * 1024), 16, 0, 0);
        }
    };
    // swizzled frag read from a 2KB ring slot (wave-private, conflict-striped)
    auto ldfrag = [&](const char* regn) {
        union { i32x8 v; int4 h2[2]; } u;
        u.h2[0] = *(const int4*)(regn + lrow * 128 + (kb        ^ ((lrow & 7) << 4)));
        u.h2[1] = *(const int4*)(regn + lrow * 128 + ((kb + 16) ^ ((lrow & 7) << 4)));
        return u.v;
    };
    auto bn_of = [&](int k) { return (bm + t0 + 8 * k) & 127; };

    // ---- prologue: A-frags (+diag B) from global FIRST, then stage 0,1 ----
    const char* Ag = gX + (size_t)bm * 8192;
    i32x8 afr[4];
#pragma unroll
    for (int m = 0; m < 4; ++m)
        afr[m] = load_frag32_g(Ag + (size_t)(m * 16 + lrow) * 128, kb);

    i32x8 db = {};
    if (h == 0)
        db = load_frag32_g(Ag + (size_t)(w * 16 + lrow) * 128, kb);

    stage(bn_of(0), &lds[w][0][0]);
    stage(bn_of(1), &lds[w][1][0]);

    // afr/db (oldest) done; 4 stage loads may remain in flight
    asm volatile("s_waitcnt vmcnt(4)" ::: "memory");

    float s_r[4][4] = {{0.f}};                   // row partials [m][j] (16 cols)

    // ---- diagonal tile (h==0): rows only ----
    if (h == 0) {
        f32x4 acc[4] = {};
#pragma unroll
        for (int m = 0; m < 4; ++m)
            acc[m] = __builtin_amdgcn_mfma_scale_f32_16x16x128_f8f6f4(
                afr[m], db, acc[m], 0, 0, 0, SCALE1, 0, SCALE1);
#pragma unroll
        for (int m = 0; m < 4; ++m)
#pragma unroll
            for (int j = 0; j < 4; ++j)
                s_r[m][j] += __builtin_amdgcn_exp2f(acc[m][j]);
    }

    // ---- main loop: 8 tiles, depth-2 prefetch, ZERO barriers ----
#pragma unroll
    for (int k = 0; k < 8; ++k) {
        if (k + 2 < 8)
            stage(bn_of(k + 2), &lds[w][(k + 2) % 3][0]);

        // wait: tile k's 2 loads landed (own wave only)
        if (k + 2 < 8)      { asm volatile("s_waitcnt vmcnt(4)" ::: "memory"); }
        else if (k + 1 < 8) { asm volatile("s_waitcnt vmcnt(2)" ::: "memory"); }
        else                { asm volatile("s_waitcnt vmcnt(0)" ::: "memory"); }

        i32x8 bfr = ldfrag(&lds[w][k % 3][0]);

        f32x4 acc[4] = {};
        __builtin_amdgcn_s_setprio(1);
#pragma unroll
        for (int m = 0; m < 4; ++m)
            acc[m] = __builtin_amdgcn_mfma_scale_f32_16x16x128_f8f6f4(
                afr[m], bfr, acc[m], 0, 0, 0, SCALE1, 0, SCALE1);
        __builtin_amdgcn_s_setprio(0);

        const float g = (k == 7) ? g7 : 1.f;
        float sc = 0.f;
#pragma unroll
        for (int m = 0; m < 4; ++m)
#pragma unroll
            for (int j = 0; j < 4; ++j) {
                float e2 = __builtin_amdgcn_exp2f(acc[m][j]) * g;
                s_r[m][j] += e2;
                sc += e2;
            }
        // col sums: reduce over 4 k-groups (lanes xor 16,32), 16 exclusive cols
        sc += __shfl_xor(sc, 16, 64);
        sc += __shfl_xor(sc, 32, 64);
        if (lane < 16) {
            int gcol = bn_of(k) * 64 + w * 16 + lane;
            atomicAdd(&R[l * B_ROWS + gcol], EULER * sc);
        }
    }

    // ---- row reduction: sum wave's 16-col partials, add per wave ----
#pragma unroll
    for (int m = 0; m < 4; ++m)
#pragma unroll
        for (int j = 0; j < 4; ++j) {
            float v = s_r[m][j];
            v += __shfl_xor(v, 1, 64);
            v += __shfl_xor(v, 2, 64);
            v += __shfl_xor(v, 4, 64);
            v += __shfl_xor(v, 8, 64);
            if ((lane & 15) == 0) {
                int grow = bm * 64 + m * 16 + (lane >> 4) * 4 + j;
                atomicAdd(&R[l * B_ROWS + grow], EULER * v);
            }
        }
}

// --------------------------- finalize --------------------------------------
__global__ void finalize_kernel(const float* __restrict__ text,
                                const float* __restrict__ shape,
                                const float* __restrict__ R,
                                float* __restrict__ out) {
    const int tid = threadIdx.x;
    const int lane = tid & 63;
    const int w = tid >> 6;
    const float inv128 = 0.0078125f;
    float accum = 0.f;

    for (int task = blockIdx.x * 4 + w; task < 2 * P_PAIRS; task += 1024) {
        int l = task >> 12;
        int p = task & (P_PAIRS - 1);
        const float* a = text + (2 * p) * E_COLS;            // even row: text
        const float* b = l ? (shape + p * E_COLS) : (text + (2 * p + 1) * E_COLS);
        float2 av = *(const float2*)(a + lane * 2);
        float2 bv = *(const float2*)(b + lane * 2);
        float dii = av.x * av.x + av.y * av.y;
        float djj = bv.x * bv.x + bv.y * bv.y;
        float dij = av.x * bv.x + av.y * bv.y;
#pragma unroll
        for (int sh = 1; sh < 64; sh <<= 1) {
            dii += __shfl_xor(dii, sh, 64);
            djj += __shfl_xor(djj, sh, 64);
            dij += __shfl_xor(dij, sh, 64);
        }
        if (lane == 0) {
            float Dii = dii * inv128, Djj = djj * inv128, Dij = dij * inv128;
            float S = R[l * B_ROWS + 2 * p] + R[l * B_ROWS + 2 * p + 1]
                    - (__expf(1.f + Dii) + 2.f * __expf(1.f + Dij) + __expf(1.f + Djj));
            float J = __logf(S) - Dij;
            accum += 0.5f * J * J * (1.0f / (float)P_PAIRS);
        }
    }

    __shared__ float red[4];
    if (lane == 0) red[w] = accum;
    __syncthreads();
    if (tid == 0) atomicAdd(out, red[0] + red[1] + red[2] + red[3]);
}

// --------------------------- launch ----------------------------------------
extern "C" void kernel_launch(void* const* d_in, const int* in_sizes, int n_in,
                              void* d_out, int out_size, void* d_ws, size_t ws_size,
                              hipStream_t stream) {
    const float* text  = (const float*)d_in[0];
    const float* shape = (const float*)d_in[1];
    float* out = (float*)d_out;
    char* ws = (char*)d_ws;

    unsigned char* Xt = (unsigned char*)ws;
    unsigned char* Xm = (unsigned char*)(ws + 1u * 1024u * 1024u);
    float* R = (float*)(ws + 2u * 1024u * 1024u);

    convert_kernel<<<(B_ROWS * E_COLS / 4 + 255) / 256, 256, 0, stream>>>(
        text, shape, (unsigned*)Xt, (unsigned*)Xm, R, out);

    dim3 grid(NSTRIP, NH, 2);                    // 128 strips x 8 splits x 2 layers
    gemm_rowsum_kernel<<<grid, 256, 0, stream>>>(Xt, Xm, R);

    finalize_kernel<<<256, 256, 0, stream>>>(text, shape, R, out);
}

// Round 15
// 40.543 us; speedup vs baseline: 2.5726x; 2.5726x over previous
//
#include <hip/hip_runtime.h>
#include <hip/hip_bf16.h>

// ---------------------------------------------------------------------------
// Metric_Loss: two fused (X X^T/128 -> exp(1+.) -> row-sum) passes + pair combine.
// B=8192, E=128, P=4096.  Output: scalar f32 = metric_tt + metric_st.
//
// Round 15: ZERO-TAIL grid. R8's proven body (MX-fp8 16x16x128, 2-phase
// counted-vmcnt, 16KB LDS, symmetry wrap-pairing) with NH=6: grid =
// 128 x 6 x 2 = 1536 blocks = EXACTLY 6 blocks/CU -- all blocks co-resident
// from t=0, makespan = 1 block-time (10-11 tiles) instead of R8's 2
// (2048 blocks on 1536 slots = 16 effective tile-times for 8 tiles of work).
// Distance partition: h in 0..5 -> t = h+1 + 6k (t=1..63 each once);
// diagonal in h==3's prologue; t=64 appended to h==4, gated to bm<64.
//
// ws layout:
//   [0, 1MB)        Xt fp8    [8192][128]   scaled by sqrt(log2e/128)
//   [1MB, 2MB)      Xm fp8    [8192][128]   (mixed: even=text, odd=shape[r>>1])
//   [2MB, 2MB+64KB) R f32     [2][8192]     row sums of exp(1+D)
// ---------------------------------------------------------------------------

#define B_ROWS 8192
#define E_COLS 128
#define P_PAIRS 4096
#define NSTRIP 128              // 64-row strips
#define NHS 6                   // h-splits per strip (zero-tail: 1536 blocks)

using f32x4 = __attribute__((ext_vector_type(4))) float;
using i32x8 = __attribute__((ext_vector_type(8))) int;

// sqrt(log2(e)/128): MFMA yields acc = D*log2(e); exp(1+D) = e * exp2(acc)
#define BF_SCALE 0.106164482742544f
#define EULER    2.718281828459045f
#define SCALE1   0x7f            // E8M0 exponent 127 -> 2^0 (unit scale)

__device__ __forceinline__ unsigned pk4_fp8(float a, float b, float c, float d) {
    unsigned v = 0;
    v = __builtin_amdgcn_cvt_pk_fp8_f32(a * BF_SCALE, b * BF_SCALE, v, false);
    v = __builtin_amdgcn_cvt_pk_fp8_f32(c * BF_SCALE, d * BF_SCALE, v, true);
    return v;
}

__device__ __forceinline__ int lds_off(int row, int k0) {
    return (row << 7) + (k0 ^ ((row & 7) << 4));
}

// K=128 fragment from swizzled LDS: 32 contiguous fp8 at (row, k32).
__device__ __forceinline__ i32x8 load_frag32(const char* base, int row, int k32) {
    union { i32x8 v; int4 h[2]; } u;
    u.h[0] = *(const int4*)(base + lds_off(row, k32));
    u.h[1] = *(const int4*)(base + lds_off(row, k32 + 16));
    return u.v;
}

// Stage one 64x128 fp8 tile (8KB): 2 iters of 256 threads x 16B.
__device__ __forceinline__ void stage8k(const char* gsrc, char* ldst, int tid) {
#pragma unroll
    for (int it = 0; it < 2; ++it) {
        int L   = it * 4096 + tid * 16;
        int row = L >> 7;
        int cb  = L & 127;
        int src = (row << 7) + (cb ^ ((row & 7) << 4));
        __builtin_amdgcn_global_load_lds(
            (const __attribute__((address_space(1))) void*)(gsrc + src),
            (__attribute__((address_space(3))) void*)(ldst + L), 16, 0, 0);
    }
}

// --------------------------- conversion kernel -----------------------------
__global__ void convert_kernel(const float* __restrict__ text,
                               const float* __restrict__ shape,
                               unsigned* __restrict__ Xt,
                               unsigned* __restrict__ Xm,
                               float* __restrict__ R,
                               float* __restrict__ out) {
    int idx = blockIdx.x * blockDim.x + threadIdx.x;     // 4 elements per thread
    if (idx >= B_ROWS * E_COLS / 4) return;
    if (idx < 4096) {                                    // zero R (2*8192 f32)
        float4 z; z.x = z.y = z.z = z.w = 0.f;
        ((float4*)R)[idx] = z;
    }
    if (idx == 0) *out = 0.f;
    int e = idx * 4;
    float4 t = *(const float4*)(text + e);
    unsigned tp = pk4_fp8(t.x, t.y, t.z, t.w);
    Xt[idx] = tp;
    int row = e >> 7;
    if (row & 1) {
        int col = e & 127;
        float4 s = *(const float4*)(shape + (row >> 1) * E_COLS + col);
        Xm[idx] = pk4_fp8(s.x, s.y, s.z, s.w);
    } else {
        Xm[idx] = tp;
    }
}

// --------------------------- fused GEMM + rowsum (MX-fp8) ------------------
// Block = (strip bm in 0..127, split h in 0..5, layer l). Strip = 64 A-rows.
// h -> distances t = h+1 + 6k (<=63): h<3 -> 11 tiles, h>=3 -> 10.
// h==3 additionally computes the diagonal (from buf0).
// h==4, bm<64 additionally appends t=64 as tile idx==10.
__launch_bounds__(256, 6)
__global__ void gemm_rowsum_kernel(const unsigned char* __restrict__ Xt,
                                   const unsigned char* __restrict__ Xm,
                                   float* __restrict__ R) {
    const int bm = blockIdx.x, h = blockIdx.y, l = blockIdx.z;
    const char* gX = (const char*)(l ? Xm : Xt);

    __shared__ __align__(16) char buf0[64 * 128];
    __shared__ __align__(16) char buf1[64 * 128];
    const int tid = threadIdx.x;

    const int t0 = h + 1;
    int N = (h < 3) ? 11 : 10;
    const bool do64 = (h == 4 && bm < 64);
    if (do64) N = 11;                            // idx==10 -> t=64

    auto tf = [&](int i) -> int { return (h == 4 && i == 10) ? 64 : (t0 + 6 * i); };

    // ---- prologue: stage A -> buf0, first B -> buf1 ----
    stage8k(gX + (size_t)bm * 8192, buf0, tid);
    stage8k(gX + (size_t)((bm + tf(0)) & 127) * 8192, buf1, tid);
    asm volatile("s_waitcnt vmcnt(2)" ::: "memory");     // A landed
    __builtin_amdgcn_s_barrier();

    const int lane = tid & 63;
    const int w  = tid >> 6;
    const int wr = w >> 1, wc = w & 1;
    const int rA0 = wr * 32 + (lane & 15);
    const int rB0 = wc * 32 + (lane & 15);
    const int k32 = (lane >> 4) * 32;            // byte offset of lane's K-slice

    // ---- hoist A fragments (2 m-frags, full K=128 each) ----
    i32x8 afr[2];
#pragma unroll
    for (int m = 0; m < 2; ++m)
        afr[m] = load_frag32(buf0, rA0 + m * 16, k32);

    float s_r[2][4] = {{0.f}};                   // persistent row partials [m][j]

    // ---- diagonal tile (h==3): B-frags also from buf0; rows only ----
    if (h == 3) {
        i32x8 bfr[2];
#pragma unroll
        for (int n = 0; n < 2; ++n)
            bfr[n] = load_frag32(buf0, rB0 + n * 16, k32);
        f32x4 acc[2][2] = {};
#pragma unroll
        for (int m = 0; m < 2; ++m)
#pragma unroll
            for (int n = 0; n < 2; ++n)
                acc[m][n] = __builtin_amdgcn_mfma_scale_f32_16x16x128_f8f6f4(
                    afr[m], bfr[n], acc[m][n], 0, 0, 0, SCALE1, 0, SCALE1);
#pragma unroll
        for (int m = 0; m < 2; ++m)
#pragma unroll
            for (int n = 0; n < 2; ++n)
#pragma unroll
                for (int j = 0; j < 4; ++j)
                    s_r[m][j] += __builtin_amdgcn_exp2f(acc[m][n][j]);
    }

    // ---- all buf0 reads done before it becomes a B buffer ----
    asm volatile("s_waitcnt lgkmcnt(0)" ::: "memory");
    __builtin_amdgcn_s_barrier();

    // ---- 2-phase pipelined loop over off-diagonal tiles ----
    int cur = 1;                                 // current B buffer: 1 -> buf1
    for (int idx = 0; idx < N; ++idx) {
        const bool hasnext = (idx + 1 < N);
        if (hasnext)
            stage8k(gX + (size_t)((bm + tf(idx + 1)) & 127) * 8192,
                    cur ? buf0 : buf1, tid);

        if (hasnext) { asm volatile("s_waitcnt vmcnt(2)" ::: "memory"); }
        else         { asm volatile("s_waitcnt vmcnt(0)" ::: "memory"); }
        __builtin_amdgcn_s_barrier();            // cur buffer staged (all waves)

        const char* lsrc = cur ? buf1 : buf0;
        i32x8 bfr[2];
#pragma unroll
        for (int n = 0; n < 2; ++n)
            bfr[n] = load_frag32(lsrc, rB0 + n * 16, k32);
        f32x4 acc[2][2] = {};
#pragma unroll
        for (int m = 0; m < 2; ++m)
#pragma unroll
            for (int n = 0; n < 2; ++n)
                acc[m][n] = __builtin_amdgcn_mfma_scale_f32_16x16x128_f8f6f4(
                    afr[m], bfr[n], acc[m][n], 0, 0, 0, SCALE1, 0, SCALE1);

        asm volatile("s_waitcnt lgkmcnt(0)" ::: "memory");
        __builtin_amdgcn_s_barrier();            // cur reads done -> overwritable

        // ---- epilogue: rows -> regs, cols -> shuffle + atomics ----
        const int bn = (bm + tf(idx)) & 127;
        float s_c[2] = {0.f, 0.f};
#pragma unroll
        for (int m = 0; m < 2; ++m)
#pragma unroll
            for (int n = 0; n < 2; ++n)
#pragma unroll
                for (int j = 0; j < 4; ++j) {
                    float e2 = __builtin_amdgcn_exp2f(acc[m][n][j]);
                    s_r[m][j] += e2;
                    s_c[n] += e2;
                }
#pragma unroll
        for (int n = 0; n < 2; ++n) {
            float v = s_c[n];
            v += __shfl_xor(v, 16, 64);
            v += __shfl_xor(v, 32, 64);
            if (lane < 16) {
                int gcol = bn * 64 + wc * 32 + n * 16 + lane;
                atomicAdd(&R[l * B_ROWS + gcol], EULER * v);
            }
        }
        cur ^= 1;
    }

    // ---- final row reduction (once per block) ----
#pragma unroll
    for (int m = 0; m < 2; ++m)
#pragma unroll
        for (int j = 0; j < 4; ++j) {
            float v = s_r[m][j];
            v += __shfl_xor(v, 1, 64);
            v += __shfl_xor(v, 2, 64);
            v += __shfl_xor(v, 4, 64);
            v += __shfl_xor(v, 8, 64);
            if ((lane & 15) == 0) {
                int grow = bm * 64 + wr * 32 + m * 16 + (lane >> 4) * 4 + j;
                atomicAdd(&R[l * B_ROWS + grow], EULER * v);
            }
        }
}

// --------------------------- finalize --------------------------------------
__global__ void finalize_kernel(const float* __restrict__ text,
                                const float* __restrict__ shape,
                                const float* __restrict__ R,
                                float* __restrict__ out) {
    const int tid = threadIdx.x;
    const int lane = tid & 63;
    const int w = tid >> 6;
    const float inv128 = 0.0078125f;
    float accum = 0.f;

    for (int task = blockIdx.x * 4 + w; task < 2 * P_PAIRS; task += 1024) {
        int l = task >> 12;
        int p = task & (P_PAIRS - 1);
        const float* a = text + (2 * p) * E_COLS;            // even row: text
        const float* b = l ? (shape + p * E_COLS) : (text + (2 * p + 1) * E_COLS);
        float2 av = *(const float2*)(a + lane * 2);
        float2 bv = *(const float2*)(b + lane * 2);
        float dii = av.x * av.x + av.y * av.y;
        float djj = bv.x * bv.x + bv.y * bv.y;
        float dij = av.x * bv.x + av.y * bv.y;
#pragma unroll
        for (int sh = 1; sh < 64; sh <<= 1) {
            dii += __shfl_xor(dii, sh, 64);
            djj += __shfl_xor(djj, sh, 64);
            dij += __shfl_xor(dij, sh, 64);
        }
        if (lane == 0) {
            float Dii = dii * inv128, Djj = djj * inv128, Dij = dij * inv128;
            float S = R[l * B_ROWS + 2 * p] + R[l * B_ROWS + 2 * p + 1]
                    - (__expf(1.f + Dii) + 2.f * __expf(1.f + Dij) + __expf(1.f + Djj));
            float J = __logf(S) - Dij;
            accum += 0.5f * J * J * (1.0f / (float)P_PAIRS);
        }
    }

    __shared__ float red[4];
    if (lane == 0) red[w] = accum;
    __syncthreads();
    if (tid == 0) atomicAdd(out, red[0] + red[1] + red[2] + red[3]);
}

// --------------------------- launch ----------------------------------------
extern "C" void kernel_launch(void* const* d_in, const int* in_sizes, int n_in,
                              void* d_out, int out_size, void* d_ws, size_t ws_size,
                              hipStream_t stream) {
    const float* text  = (const float*)d_in[0];
    const float* shape = (const float*)d_in[1];
    float* out = (float*)d_out;
    char* ws = (char*)d_ws;

    unsigned char* Xt = (unsigned char*)ws;
    unsigned char* Xm = (unsigned char*)(ws + 1u * 1024u * 1024u);
    float* R = (float*)(ws + 2u * 1024u * 1024u);

    convert_kernel<<<(B_ROWS * E_COLS / 4 + 255) / 256, 256, 0, stream>>>(
        text, shape, (unsigned*)Xt, (unsigned*)Xm, R, out);

    dim3 grid(NSTRIP, NHS, 2);                   // 128 strips x 6 splits x 2 layers
    gemm_rowsum_kernel<<<grid, 256, 0, stream>>>(Xt, Xm, R);

    finalize_kernel<<<256, 256, 0, stream>>>(text, shape, R, out);
}